// Round 12
// baseline (379.706 us; speedup 1.0000x reference)
//
#include <hip/hip_runtime.h>

// Stream_PreNet as ONE composed 7x7 conv (exact algebra, proven R11), now on
// mfma_f32_32x32x16_bf16: per 1024B LDS read the MFMA does 2x the FLOPs of
// 16x16x32 -> LDS-unit time (R11's dominant resource, ~100us/CU) halves.
// Geometry: block = 32 pix x 16 rows x 96 ch; 6 waves = 3 ch-tiles x 2 row-grps.
// Per wave: 2 quads of 4 rows; 25 K-slices (KP=400); 4 indep acc chains
// (f32x16 x4, named, static idx); weights 5 frags/pass, phase-local.
// Pair-49 (zero-weight pad) B-address clamped to pair 48: in-bounds, finite,
// x0 weight -> no OOB, no NaN (R3 lesson), no guard branch.
// Layouts (m74/m101 verified): A[m=lane&31][k=8hi+j]; B[k=8hi+j][n=lane&31];
// D: col=lane&31, row=(reg&3)+8(reg>>2)+4hi.
// d_ws: wct (96*400 bf16 = 76,800B) + bias2e (96 f32) = 77,184 B.

#define B_   8
#define H_   512
#define W_   256
#define CIN  8
#define COUT 96
#define TH   16           // output rows per block
#define TW   32           // output cols per block
#define RS   (TH + 6)     // 22 staged x rows
#define XC   (TW + 6)     // 38 staged x cols
#define KP   400          // padded K (25 slices of 16)
#define NTHREADS 384      // 6 waves

typedef __bf16 bf16x8 __attribute__((ext_vector_type(8)));
typedef float  f32x4  __attribute__((ext_vector_type(4)));
typedef float  f32x16 __attribute__((ext_vector_type(16)));
typedef int    i32x4  __attribute__((ext_vector_type(4)));

__device__ __forceinline__ unsigned short f2bf(float f) {
  unsigned u = __builtin_bit_cast(unsigned, f);
  u += 0x7FFFu + ((u >> 16) & 1u);   // RNE
  return (unsigned short)(u >> 16);
}

__device__ __forceinline__ bf16x8 ld16s(const unsigned short* p) {
  i32x4 t = *(const i32x4*)p;        // 16B load -> ds_read_b128 / dwordx4
  return __builtin_bit_cast(bf16x8, t);
}

__device__ __forceinline__ f32x16 mfma32(bf16x8 a, bf16x8 b, f32x16 c) {
  return __builtin_amdgcn_mfma_f32_32x32x16_bf16(a, b, c, 0, 0, 0);
}

// jnp.pad mode='symmetric': -1->0, -2->1 ; N->N-1, N+1->N-2
__device__ __forceinline__ int symH(int i) { return i < 0 ? -1 - i : (i >= H_ ? 2 * H_ - 1 - i : i); }
__device__ __forceinline__ int symW(int i) { return i < 0 ? -1 - i : (i >= W_ ? 2 * W_ - 1 - i : i); }

// ---- prep: compose Wc = W2(7x1) o W1(1x7) in fp32, cast once to bf16 ----
// wct[n][k], k = p*8 + c, p = th*7+tw (p>=49 zero).  bias2e = b2 + fold(b1).
__global__ void prep_kernel(const float* __restrict__ W1, const float* __restrict__ b1,
                            const float* __restrict__ W2, const float* __restrict__ b2,
                            unsigned short* __restrict__ wct, float* __restrict__ bias2e) {
  int i = blockIdx.x * 256 + threadIdx.x;      // 150 blocks x 256 = 96*400 exactly
  if (i < 96 * KP) {
    int n = i / KP, k = i - n * KP;
    int p = k >> 3, c = k & 7;
    float s = 0.f;
    if (p < 49) {
      int th = p / 7, tw = p - 7 * th;
#pragma unroll 8
      for (int m = 0; m < 96; ++m)             // W2[(th*96+m)*96+n] * W1[(tw*8+c)*96+m]
        s += W2[(th * 96 + m) * 96 + n] * W1[(tw * 8 + c) * 96 + m];
    }
    wct[i] = f2bf(s);
  }
  if (i < 96) {
    float s = b2[i];
#pragma unroll 8
    for (int kc = 0; kc < 672; ++kc) {
      int m = kc - (kc / 96) * 96;
      s += W2[kc * 96 + i] * b1[m];
    }
    bias2e[i] = s;
  }
}

__global__ __launch_bounds__(NTHREADS, 4)      // VGPR cap 128 (live ~112)
void conv7(const float* __restrict__ x, const unsigned short* __restrict__ wct,
           const float* __restrict__ bias2e, float* __restrict__ out) {
  __shared__ __align__(16) unsigned short xt[RS][XC][CIN];   // 13,376 B

  const int tid = threadIdx.x;
  const int w0  = blockIdx.x * TW;
  const int h0  = blockIdx.y * TH;
  const int b   = blockIdx.z;

  const int wid  = tid >> 6;        // wave id
  const int lane = tid & 63;
  const int l31  = lane & 31;       // A: ch-in-tile / B,D: pixel
  const int hi   = lane >> 5;       // k-half
  const int cht  = wid >> 1;        // channel tile 0..2 (32 ch each)
  const int rg   = wid & 1;         // row group 0..1 (8 rows each)
  const int ch   = cht * 32 + l31;  // A channel row

  // ---- stage x halo tile (symmetric pad applied), fp32 -> bf16 ----
  const float* xb = x + (size_t)b * H_ * W_ * CIN;
  for (int idx = tid; idx < RS * XC; idx += NTHREADS) {
    int rr = idx / XC, cc = idx - rr * XC;
    int hr = symH(h0 - 3 + rr);
    int wc = symW(w0 - 3 + cc);
    const float4* px = (const float4*)(xb + ((size_t)hr * W_ + wc) * CIN);
    float4 v0 = px[0], v1 = px[1];
    unsigned p0 = ((unsigned)f2bf(v0.y) << 16) | f2bf(v0.x);
    unsigned p1 = ((unsigned)f2bf(v0.w) << 16) | f2bf(v0.z);
    unsigned p2 = ((unsigned)f2bf(v1.y) << 16) | f2bf(v1.x);
    unsigned p3 = ((unsigned)f2bf(v1.w) << 16) | f2bf(v1.z);
    *(i32x4*)&xt[rr][cc][0] = (i32x4){(int)p0, (int)p1, (int)p2, (int)p3};
  }

  const unsigned short* wrow = wct + (size_t)ch * KP;
  const unsigned short* xtf  = &xt[0][0][0];

  __syncthreads();

#define ROWSTR (XC * CIN)            // 304 elements per staged row

#pragma unroll 1
  for (int qr = 0; qr < 2; ++qr) {   // two quads of 4 rows per wave
    const int m0 = rg * 8 + qr * 4;  // first output row of this quad
    f32x16 acc0 = {}, acc1 = {}, acc2 = {}, acc3 = {};
    const int mbase = m0 * ROWSTR + l31 * CIN;

#pragma unroll 1                     // phase-local weight sets (5 frags = 20 VGPR)
    for (int sp = 0; sp < 5; ++sp) {
      bf16x8 wf[5];
#pragma unroll
      for (int s2 = 0; s2 < 5; ++s2)         // A-frag: wct[ch][16s + 8hi ..+7]
        wf[s2] = ld16s(&wrow[80 * sp + 16 * s2 + 8 * hi]);
#pragma unroll
      for (int s2 = 0; s2 < 5; ++s2) {
        int p = 10 * sp + 2 * s2 + hi;       // pair index 0..49
        int pc = p > 48 ? 48 : p;            // pair 49: zero weight; clamp addr
        int th = (pc * 9363) >> 16;          // /7 magic (exact for pc<=48)
        int tw = pc - 7 * th;
        const unsigned short* bp = xtf + mbase + th * ROWSTR + tw * CIN;
        acc0 = mfma32(wf[s2], ld16s(bp), acc0);
        acc1 = mfma32(wf[s2], ld16s(bp + ROWSTR), acc1);
        acc2 = mfma32(wf[s2], ld16s(bp + 2 * ROWSTR), acc2);
        acc3 = mfma32(wf[s2], ld16s(bp + 3 * ROWSTR), acc3);
      }
    }

    // ---- epilogue: D col=l31 (pixel), rows (reg&3)+8*(reg>>2)+4hi (channel) ----
#define EPI(R, ACC)                                                              \
    {                                                                            \
      const size_t ob = (((size_t)b * H_ + h0 + m0 + (R)) * W_ + w0 + l31) * COUT \
                        + cht * 32 + 4 * hi;                                     \
      _Pragma("unroll")                                                          \
      for (int q = 0; q < 4; ++q) {                                              \
        const float4 bia = *(const float4*)&bias2e[cht * 32 + 8 * q + 4 * hi];   \
        f32x4 v = {(ACC)[4 * q] + bia.x, (ACC)[4 * q + 1] + bia.y,               \
                   (ACC)[4 * q + 2] + bia.z, (ACC)[4 * q + 3] + bia.w};          \
        __builtin_nontemporal_store(v, (f32x4*)(out + ob + 8 * q));              \
      }                                                                          \
    }
    EPI(0, acc0) EPI(1, acc1) EPI(2, acc2) EPI(3, acc3)
#undef EPI
  }
}

extern "C" void kernel_launch(void* const* d_in, const int* in_sizes, int n_in,
                              void* d_out, int out_size, void* d_ws, size_t ws_size,
                              hipStream_t stream) {
  const float* x  = (const float*)d_in[0];
  const float* W1 = (const float*)d_in[1];
  const float* b1 = (const float*)d_in[2];
  const float* W2 = (const float*)d_in[3];
  const float* b2 = (const float*)d_in[4];
  // d_in[5] = training (unused)

  unsigned short* wct = (unsigned short*)d_ws;       // 96*400 u16
  float* bias2e = (float*)(wct + 96 * KP);           // 96 f32
  float* out = (float*)d_out;

  prep_kernel<<<dim3(150), dim3(256), 0, stream>>>(W1, b1, W2, b2, wct, bias2e);
  conv7<<<dim3(W_ / TW, H_ / TH, B_), dim3(NTHREADS), 0, stream>>>(
      x, wct, bias2e, out);
}

// Round 13
// 348.629 us; speedup vs baseline: 1.0891x; 1.0891x over previous
//
#include <hip/hip_runtime.h>

// Stream_PreNet as ONE composed 7x7 conv (exact algebra, proven R11/R12),
// mfma_f32_32x32x16_bf16 (2x FLOPs per 1024B LDS read vs 16x16x32).
// R13 = R12 with ROW-PAIR sub-passes: acc live set 32 VGPR (2x f32x16), not 64
// (R12's acc spill: VGPR=64, +450MB scratch WRITE, MfmaUtil 8.8%).
// Same LDS traffic (B-reads are per-row-per-slice regardless of rows in
// flight): reads/pixel 2.34 vs R11's 4.9.
// Geometry: block = 32 pix x 16 rows x 96 ch; 6 waves = 3 ch-tiles x 2 row-grps;
// each wave: 4 sub-passes of 2 rows; 25 K-slices (KP=400); weights 5 frags/set,
// phase-local (unroll-1). Pair-49 (zero pad) B-addr clamped to pair 48 (valid,
// finite, x0 weight -> no OOB/NaN). Layouts (m74/m101): A[m=ch][k=8hi+j];
// B[k][n=pix l31]; D col=l31, row=(reg&3)+8(reg>>2)+4hi.
// d_ws: wct (96*400 bf16 = 76,800B) + bias2e (96 f32) = 77,184 B.

#define B_   8
#define H_   512
#define W_   256
#define CIN  8
#define COUT 96
#define TH   16           // output rows per block
#define TW   32           // output cols per block
#define RS   (TH + 6)     // 22 staged x rows
#define XC   (TW + 6)     // 38 staged x cols
#define KP   400          // padded K (25 slices of 16)
#define NTHREADS 384      // 6 waves

typedef __bf16 bf16x8 __attribute__((ext_vector_type(8)));
typedef float  f32x4  __attribute__((ext_vector_type(4)));
typedef float  f32x16 __attribute__((ext_vector_type(16)));
typedef int    i32x4  __attribute__((ext_vector_type(4)));

__device__ __forceinline__ unsigned short f2bf(float f) {
  unsigned u = __builtin_bit_cast(unsigned, f);
  u += 0x7FFFu + ((u >> 16) & 1u);   // RNE
  return (unsigned short)(u >> 16);
}

__device__ __forceinline__ bf16x8 ld16s(const unsigned short* p) {
  i32x4 t = *(const i32x4*)p;        // 16B load -> ds_read_b128 / dwordx4
  return __builtin_bit_cast(bf16x8, t);
}

__device__ __forceinline__ f32x16 mfma32(bf16x8 a, bf16x8 b, f32x16 c) {
  return __builtin_amdgcn_mfma_f32_32x32x16_bf16(a, b, c, 0, 0, 0);
}

// jnp.pad mode='symmetric': -1->0, -2->1 ; N->N-1, N+1->N-2
__device__ __forceinline__ int symH(int i) { return i < 0 ? -1 - i : (i >= H_ ? 2 * H_ - 1 - i : i); }
__device__ __forceinline__ int symW(int i) { return i < 0 ? -1 - i : (i >= W_ ? 2 * W_ - 1 - i : i); }

// ---- prep: compose Wc = W2(7x1) o W1(1x7) in fp32, cast once to bf16 ----
// wct[n][k], k = p*8 + c, p = th*7+tw (p>=49 zero).  bias2e = b2 + fold(b1).
__global__ void prep_kernel(const float* __restrict__ W1, const float* __restrict__ b1,
                            const float* __restrict__ W2, const float* __restrict__ b2,
                            unsigned short* __restrict__ wct, float* __restrict__ bias2e) {
  int i = blockIdx.x * 256 + threadIdx.x;      // 150 blocks x 256 = 96*400 exactly
  if (i < 96 * KP) {
    int n = i / KP, k = i - n * KP;
    int p = k >> 3, c = k & 7;
    float s = 0.f;
    if (p < 49) {
      int th = p / 7, tw = p - 7 * th;
#pragma unroll 8
      for (int m = 0; m < 96; ++m)             // W2[(th*96+m)*96+n] * W1[(tw*8+c)*96+m]
        s += W2[(th * 96 + m) * 96 + n] * W1[(tw * 8 + c) * 96 + m];
    }
    wct[i] = f2bf(s);
  }
  if (i < 96) {
    float s = b2[i];
#pragma unroll 8
    for (int kc = 0; kc < 672; ++kc) {
      int m = kc - (kc / 96) * 96;
      s += W2[kc * 96 + i] * b1[m];
    }
    bias2e[i] = s;
  }
}

__global__ __launch_bounds__(NTHREADS, 4)      // VGPR cap 128; live ~90
void conv7(const float* __restrict__ x, const unsigned short* __restrict__ wct,
           const float* __restrict__ bias2e, float* __restrict__ out) {
  __shared__ __align__(16) unsigned short xt[RS][XC][CIN];   // 13,376 B

  const int tid = threadIdx.x;
  const int w0  = blockIdx.x * TW;
  const int h0  = blockIdx.y * TH;
  const int b   = blockIdx.z;

  const int wid  = tid >> 6;        // wave id
  const int lane = tid & 63;
  const int l31  = lane & 31;       // A: ch-in-tile / B,D: pixel
  const int hi   = lane >> 5;       // k-half
  const int cht  = wid >> 1;        // channel tile 0..2 (32 ch each)
  const int rg   = wid & 1;         // row group 0..1 (8 rows each)
  const int ch   = cht * 32 + l31;  // A channel row

  // ---- stage x halo tile (symmetric pad applied), fp32 -> bf16 ----
  const float* xb = x + (size_t)b * H_ * W_ * CIN;
  for (int idx = tid; idx < RS * XC; idx += NTHREADS) {
    int rr = idx / XC, cc = idx - rr * XC;
    int hr = symH(h0 - 3 + rr);
    int wc = symW(w0 - 3 + cc);
    const float4* px = (const float4*)(xb + ((size_t)hr * W_ + wc) * CIN);
    float4 v0 = px[0], v1 = px[1];
    unsigned p0 = ((unsigned)f2bf(v0.y) << 16) | f2bf(v0.x);
    unsigned p1 = ((unsigned)f2bf(v0.w) << 16) | f2bf(v0.z);
    unsigned p2 = ((unsigned)f2bf(v1.y) << 16) | f2bf(v1.x);
    unsigned p3 = ((unsigned)f2bf(v1.w) << 16) | f2bf(v1.z);
    *(i32x4*)&xt[rr][cc][0] = (i32x4){(int)p0, (int)p1, (int)p2, (int)p3};
  }

  const unsigned short* wrow = wct + (size_t)ch * KP;
  const unsigned short* xtf  = &xt[0][0][0];

  __syncthreads();

#define ROWSTR (XC * CIN)            // 304 elements per staged row

#pragma unroll 1
  for (int sub = 0; sub < 4; ++sub) {        // row pair: m0, m0+1
    const int m0 = rg * 8 + sub * 2;
    f32x16 acc0 = {}, acc1 = {};
    const int mbase = m0 * ROWSTR + l31 * CIN;

#pragma unroll 1                     // phase-local weight sets (5 frags = 20 VGPR)
    for (int sp = 0; sp < 5; ++sp) {
      bf16x8 wf[5];
#pragma unroll
      for (int s2 = 0; s2 < 5; ++s2)         // A-frag: wct[ch][16s + 8hi ..+7]
        wf[s2] = ld16s(&wrow[80 * sp + 16 * s2 + 8 * hi]);
#pragma unroll
      for (int s2 = 0; s2 < 5; ++s2) {
        int p = 10 * sp + 2 * s2 + hi;       // pair index 0..49
        int pc = p > 48 ? 48 : p;            // pair 49: zero weight; clamp addr
        int th = (pc * 9363) >> 16;          // /7 magic (exact for pc<=48)
        int tw = pc - 7 * th;
        const unsigned short* bp = xtf + mbase + th * ROWSTR + tw * CIN;
        acc0 = mfma32(wf[s2], ld16s(bp), acc0);
        acc1 = mfma32(wf[s2], ld16s(bp + ROWSTR), acc1);
      }
    }

    // ---- epilogue: D col=l31 (pixel), ch rows (reg&3)+8*(reg>>2)+4hi ----
#define EPI(R, ACC)                                                               \
    {                                                                             \
      const size_t ob = (((size_t)b * H_ + h0 + m0 + (R)) * W_ + w0 + l31) * COUT \
                        + cht * 32 + 4 * hi;                                      \
      _Pragma("unroll")                                                           \
      for (int q = 0; q < 4; ++q) {                                               \
        const float4 bia = *(const float4*)&bias2e[cht * 32 + 8 * q + 4 * hi];    \
        f32x4 v = {(ACC)[4 * q] + bia.x, (ACC)[4 * q + 1] + bia.y,                \
                   (ACC)[4 * q + 2] + bia.z, (ACC)[4 * q + 3] + bia.w};           \
        __builtin_nontemporal_store(v, (f32x4*)(out + ob + 8 * q));               \
      }                                                                           \
    }
    EPI(0, acc0) EPI(1, acc1)
#undef EPI
  }
}

extern "C" void kernel_launch(void* const* d_in, const int* in_sizes, int n_in,
                              void* d_out, int out_size, void* d_ws, size_t ws_size,
                              hipStream_t stream) {
  const float* x  = (const float*)d_in[0];
  const float* W1 = (const float*)d_in[1];
  const float* b1 = (const float*)d_in[2];
  const float* W2 = (const float*)d_in[3];
  const float* b2 = (const float*)d_in[4];
  // d_in[5] = training (unused)

  unsigned short* wct = (unsigned short*)d_ws;       // 96*400 u16
  float* bias2e = (float*)(wct + 96 * KP);           // 96 f32
  float* out = (float*)d_out;

  prep_kernel<<<dim3(150), dim3(256), 0, stream>>>(W1, b1, W2, b2, wct, bias2e);
  conv7<<<dim3(W_ / TW, H_ / TH, B_), dim3(NTHREADS), 0, stream>>>(
      x, wct, bias2e, out);
}

// Round 14
// 202.299 us; speedup vs baseline: 1.8770x; 1.7233x over previous
//
#include <hip/hip_runtime.h>

// Stream_PreNet as ONE composed 7x7 conv (exact algebra, proven R11-R13),
// mfma_f32_32x32x16_bf16 (2x FLOPs per 1024B LDS read vs 16x16x32).
// R14 = R13 with PLAIN cached stores instead of nontemporal.
// R13 post-mortem: NT f32x4 stores in the TW=32 epilogue have only 32B
// contiguity per instruction (hi-lane pairs) -> NT streams 32B sectors ->
// WRITE_SIZE 826MB = 2.05x output, hbm 2.5TB/s -> kernel was write-bound at
// 337us. Plain stores let L2 assemble full lines (R2 precedent: exactly 403MB).
// Geometry: block = 32 pix x 16 rows x 96 ch; 6 waves = 3 ch-tiles x 2 row-grps;
// each wave: 4 sub-passes of 2 rows (acc = 2x f32x16, AGPR-resident);
// 25 K-slices (KP=400); weights 5 frags/set, phase-local (unroll-1).
// Pair-49 (zero pad) B-addr clamped to pair 48 (valid, finite, x0 weight).
// Layouts (m74/m101): A[m=ch][k=8hi+j]; B[k][n=pix l31]; D col=l31,
// row=(reg&3)+8(reg>>2)+4hi.
// d_ws: wct (96*400 bf16 = 76,800B) + bias2e (96 f32) = 77,184 B.

#define B_   8
#define H_   512
#define W_   256
#define CIN  8
#define COUT 96
#define TH   16           // output rows per block
#define TW   32           // output cols per block
#define RS   (TH + 6)     // 22 staged x rows
#define XC   (TW + 6)     // 38 staged x cols
#define KP   400          // padded K (25 slices of 16)
#define NTHREADS 384      // 6 waves

typedef __bf16 bf16x8 __attribute__((ext_vector_type(8)));
typedef float  f32x4  __attribute__((ext_vector_type(4)));
typedef float  f32x16 __attribute__((ext_vector_type(16)));
typedef int    i32x4  __attribute__((ext_vector_type(4)));

__device__ __forceinline__ unsigned short f2bf(float f) {
  unsigned u = __builtin_bit_cast(unsigned, f);
  u += 0x7FFFu + ((u >> 16) & 1u);   // RNE
  return (unsigned short)(u >> 16);
}

__device__ __forceinline__ bf16x8 ld16s(const unsigned short* p) {
  i32x4 t = *(const i32x4*)p;        // 16B load -> ds_read_b128 / dwordx4
  return __builtin_bit_cast(bf16x8, t);
}

__device__ __forceinline__ f32x16 mfma32(bf16x8 a, bf16x8 b, f32x16 c) {
  return __builtin_amdgcn_mfma_f32_32x32x16_bf16(a, b, c, 0, 0, 0);
}

// jnp.pad mode='symmetric': -1->0, -2->1 ; N->N-1, N+1->N-2
__device__ __forceinline__ int symH(int i) { return i < 0 ? -1 - i : (i >= H_ ? 2 * H_ - 1 - i : i); }
__device__ __forceinline__ int symW(int i) { return i < 0 ? -1 - i : (i >= W_ ? 2 * W_ - 1 - i : i); }

// ---- prep: compose Wc = W2(7x1) o W1(1x7) in fp32, cast once to bf16 ----
// wct[n][k], k = p*8 + c, p = th*7+tw (p>=49 zero).  bias2e = b2 + fold(b1).
__global__ void prep_kernel(const float* __restrict__ W1, const float* __restrict__ b1,
                            const float* __restrict__ W2, const float* __restrict__ b2,
                            unsigned short* __restrict__ wct, float* __restrict__ bias2e) {
  int i = blockIdx.x * 256 + threadIdx.x;      // 150 blocks x 256 = 96*400 exactly
  if (i < 96 * KP) {
    int n = i / KP, k = i - n * KP;
    int p = k >> 3, c = k & 7;
    float s = 0.f;
    if (p < 49) {
      int th = p / 7, tw = p - 7 * th;
#pragma unroll 8
      for (int m = 0; m < 96; ++m)             // W2[(th*96+m)*96+n] * W1[(tw*8+c)*96+m]
        s += W2[(th * 96 + m) * 96 + n] * W1[(tw * 8 + c) * 96 + m];
    }
    wct[i] = f2bf(s);
  }
  if (i < 96) {
    float s = b2[i];
#pragma unroll 8
    for (int kc = 0; kc < 672; ++kc) {
      int m = kc - (kc / 96) * 96;
      s += W2[kc * 96 + i] * b1[m];
    }
    bias2e[i] = s;
  }
}

__global__ __launch_bounds__(NTHREADS, 4)      // VGPR cap 128
void conv7(const float* __restrict__ x, const unsigned short* __restrict__ wct,
           const float* __restrict__ bias2e, float* __restrict__ out) {
  __shared__ __align__(16) unsigned short xt[RS][XC][CIN];   // 13,376 B

  const int tid = threadIdx.x;
  const int w0  = blockIdx.x * TW;
  const int h0  = blockIdx.y * TH;
  const int b   = blockIdx.z;

  const int wid  = tid >> 6;        // wave id
  const int lane = tid & 63;
  const int l31  = lane & 31;       // A: ch-in-tile / B,D: pixel
  const int hi   = lane >> 5;       // k-half
  const int cht  = wid >> 1;        // channel tile 0..2 (32 ch each)
  const int rg   = wid & 1;         // row group 0..1 (8 rows each)
  const int ch   = cht * 32 + l31;  // A channel row

  // ---- stage x halo tile (symmetric pad applied), fp32 -> bf16 ----
  const float* xb = x + (size_t)b * H_ * W_ * CIN;
  for (int idx = tid; idx < RS * XC; idx += NTHREADS) {
    int rr = idx / XC, cc = idx - rr * XC;
    int hr = symH(h0 - 3 + rr);
    int wc = symW(w0 - 3 + cc);
    const float4* px = (const float4*)(xb + ((size_t)hr * W_ + wc) * CIN);
    float4 v0 = px[0], v1 = px[1];
    unsigned p0 = ((unsigned)f2bf(v0.y) << 16) | f2bf(v0.x);
    unsigned p1 = ((unsigned)f2bf(v0.w) << 16) | f2bf(v0.z);
    unsigned p2 = ((unsigned)f2bf(v1.y) << 16) | f2bf(v1.x);
    unsigned p3 = ((unsigned)f2bf(v1.w) << 16) | f2bf(v1.z);
    *(i32x4*)&xt[rr][cc][0] = (i32x4){(int)p0, (int)p1, (int)p2, (int)p3};
  }

  const unsigned short* wrow = wct + (size_t)ch * KP;
  const unsigned short* xtf  = &xt[0][0][0];

  __syncthreads();

#define ROWSTR (XC * CIN)            // 304 elements per staged row

#pragma unroll 1
  for (int sub = 0; sub < 4; ++sub) {        // row pair: m0, m0+1
    const int m0 = rg * 8 + sub * 2;
    f32x16 acc0 = {}, acc1 = {};
    const int mbase = m0 * ROWSTR + l31 * CIN;

#pragma unroll 1                     // phase-local weight sets (5 frags = 20 VGPR)
    for (int sp = 0; sp < 5; ++sp) {
      bf16x8 wf[5];
#pragma unroll
      for (int s2 = 0; s2 < 5; ++s2)         // A-frag: wct[ch][16s + 8hi ..+7]
        wf[s2] = ld16s(&wrow[80 * sp + 16 * s2 + 8 * hi]);
#pragma unroll
      for (int s2 = 0; s2 < 5; ++s2) {
        int p = 10 * sp + 2 * s2 + hi;       // pair index 0..49
        int pc = p > 48 ? 48 : p;            // pair 49: zero weight; clamp addr
        int th = (pc * 9363) >> 16;          // /7 magic (exact for pc<=48)
        int tw = pc - 7 * th;
        const unsigned short* bp = xtf + mbase + th * ROWSTR + tw * CIN;
        acc0 = mfma32(wf[s2], ld16s(bp), acc0);
        acc1 = mfma32(wf[s2], ld16s(bp + ROWSTR), acc1);
      }
    }

    // ---- epilogue: D col=l31 (pixel), ch rows (reg&3)+8*(reg>>2)+4hi ----
    // PLAIN stores (no NT): 32B-contiguity per instruction -> L2 assembles
    // full lines; NT here caused 2x sector write amplification (R13).
#define EPI(R, ACC)                                                               \
    {                                                                             \
      const size_t ob = (((size_t)b * H_ + h0 + m0 + (R)) * W_ + w0 + l31) * COUT \
                        + cht * 32 + 4 * hi;                                      \
      _Pragma("unroll")                                                           \
      for (int q = 0; q < 4; ++q) {                                               \
        const float4 bia = *(const float4*)&bias2e[cht * 32 + 8 * q + 4 * hi];    \
        f32x4 v = {(ACC)[4 * q] + bia.x, (ACC)[4 * q + 1] + bia.y,                \
                   (ACC)[4 * q + 2] + bia.z, (ACC)[4 * q + 3] + bia.w};           \
        *(f32x4*)(out + ob + 8 * q) = v;                                          \
      }                                                                           \
    }
    EPI(0, acc0) EPI(1, acc1)
#undef EPI
  }
}

extern "C" void kernel_launch(void* const* d_in, const int* in_sizes, int n_in,
                              void* d_out, int out_size, void* d_ws, size_t ws_size,
                              hipStream_t stream) {
  const float* x  = (const float*)d_in[0];
  const float* W1 = (const float*)d_in[1];
  const float* b1 = (const float*)d_in[2];
  const float* W2 = (const float*)d_in[3];
  const float* b2 = (const float*)d_in[4];
  // d_in[5] = training (unused)

  unsigned short* wct = (unsigned short*)d_ws;       // 96*400 u16
  float* bias2e = (float*)(wct + 96 * KP);           // 96 f32
  float* out = (float*)d_out;

  prep_kernel<<<dim3(150), dim3(256), 0, stream>>>(W1, b1, W2, b2, wct, bias2e);
  conv7<<<dim3(W_ / TW, H_ / TH, B_), dim3(NTHREADS), 0, stream>>>(
      x, wct, bias2e, out);
}

// Round 15
// 170.501 us; speedup vs baseline: 2.2270x; 1.1865x over previous
//
#include <hip/hip_runtime.h>

// Stream_PreNet as ONE composed 7x7 conv (exact algebra, proven R11-R14),
// mfma_f32_32x32x16_bf16.
// R15 = R12 geometry + PLAIN stores (R12/R13's 350-380us was NT 32B-sector
// write amplification -- WRITE 2x output at 2.5TB/s -- NOT acc spill; R2/R14
// prove plain stores merge to exactly 1x in L2).
// 2 sub-passes x 4 rows: acc = 4x f32x16 (AGPR-resident), weight phases 10
// (was 20 in R14) and per-phase work 2x (20 MFMA + 20 ds_read ~ 320cyc)
// covers the ~250cyc L2 weight-load latency -> fewer serial stalls.
// Geometry: block = 32 pix x 16 rows x 96 ch; 6 waves = 3 ch-tiles x 2 row-grps.
// Pair-49 (zero pad) B-addr clamped to pair 48 (valid, finite, x0 weight).
// Layouts (m74/m101): A[m=ch][k=8hi+j]; B[k][n=pix l31]; D col=l31,
// row=(reg&3)+8(reg>>2)+4hi.
// d_ws: wct (96*400 bf16 = 76,800B) + bias2e (96 f32) = 77,184 B.

#define B_   8
#define H_   512
#define W_   256
#define CIN  8
#define COUT 96
#define TH   16           // output rows per block
#define TW   32           // output cols per block
#define RS   (TH + 6)     // 22 staged x rows
#define XC   (TW + 6)     // 38 staged x cols
#define KP   400          // padded K (25 slices of 16)
#define NTHREADS 384      // 6 waves

typedef __bf16 bf16x8 __attribute__((ext_vector_type(8)));
typedef float  f32x4  __attribute__((ext_vector_type(4)));
typedef float  f32x16 __attribute__((ext_vector_type(16)));
typedef int    i32x4  __attribute__((ext_vector_type(4)));

__device__ __forceinline__ unsigned short f2bf(float f) {
  unsigned u = __builtin_bit_cast(unsigned, f);
  u += 0x7FFFu + ((u >> 16) & 1u);   // RNE
  return (unsigned short)(u >> 16);
}

__device__ __forceinline__ bf16x8 ld16s(const unsigned short* p) {
  i32x4 t = *(const i32x4*)p;        // 16B load -> ds_read_b128 / dwordx4
  return __builtin_bit_cast(bf16x8, t);
}

__device__ __forceinline__ f32x16 mfma32(bf16x8 a, bf16x8 b, f32x16 c) {
  return __builtin_amdgcn_mfma_f32_32x32x16_bf16(a, b, c, 0, 0, 0);
}

// jnp.pad mode='symmetric': -1->0, -2->1 ; N->N-1, N+1->N-2
__device__ __forceinline__ int symH(int i) { return i < 0 ? -1 - i : (i >= H_ ? 2 * H_ - 1 - i : i); }
__device__ __forceinline__ int symW(int i) { return i < 0 ? -1 - i : (i >= W_ ? 2 * W_ - 1 - i : i); }

// ---- prep: compose Wc = W2(7x1) o W1(1x7) in fp32, cast once to bf16 ----
// wct[n][k], k = p*8 + c, p = th*7+tw (p>=49 zero).  bias2e = b2 + fold(b1).
__global__ void prep_kernel(const float* __restrict__ W1, const float* __restrict__ b1,
                            const float* __restrict__ W2, const float* __restrict__ b2,
                            unsigned short* __restrict__ wct, float* __restrict__ bias2e) {
  int i = blockIdx.x * 256 + threadIdx.x;      // 150 blocks x 256 = 96*400 exactly
  if (i < 96 * KP) {
    int n = i / KP, k = i - n * KP;
    int p = k >> 3, c = k & 7;
    float s = 0.f;
    if (p < 49) {
      int th = p / 7, tw = p - 7 * th;
#pragma unroll 8
      for (int m = 0; m < 96; ++m)             // W2[(th*96+m)*96+n] * W1[(tw*8+c)*96+m]
        s += W2[(th * 96 + m) * 96 + n] * W1[(tw * 8 + c) * 96 + m];
    }
    wct[i] = f2bf(s);
  }
  if (i < 96) {
    float s = b2[i];
#pragma unroll 8
    for (int kc = 0; kc < 672; ++kc) {
      int m = kc - (kc / 96) * 96;
      s += W2[kc * 96 + i] * b1[m];
    }
    bias2e[i] = s;
  }
}

__global__ __launch_bounds__(NTHREADS, 4)      // 128 VGPR+AGPR budget/wave
void conv7(const float* __restrict__ x, const unsigned short* __restrict__ wct,
           const float* __restrict__ bias2e, float* __restrict__ out) {
  __shared__ __align__(16) unsigned short xt[RS][XC][CIN];   // 13,376 B

  const int tid = threadIdx.x;
  const int w0  = blockIdx.x * TW;
  const int h0  = blockIdx.y * TH;
  const int b   = blockIdx.z;

  const int wid  = tid >> 6;        // wave id
  const int lane = tid & 63;
  const int l31  = lane & 31;       // A: ch-in-tile / B,D: pixel
  const int hi   = lane >> 5;       // k-half
  const int cht  = wid >> 1;        // channel tile 0..2 (32 ch each)
  const int rg   = wid & 1;         // row group 0..1 (8 rows each)
  const int ch   = cht * 32 + l31;  // A channel row

  // ---- stage x halo tile (symmetric pad applied), fp32 -> bf16 ----
  const float* xb = x + (size_t)b * H_ * W_ * CIN;
  for (int idx = tid; idx < RS * XC; idx += NTHREADS) {
    int rr = idx / XC, cc = idx - rr * XC;
    int hr = symH(h0 - 3 + rr);
    int wc = symW(w0 - 3 + cc);
    const float4* px = (const float4*)(xb + ((size_t)hr * W_ + wc) * CIN);
    float4 v0 = px[0], v1 = px[1];
    unsigned p0 = ((unsigned)f2bf(v0.y) << 16) | f2bf(v0.x);
    unsigned p1 = ((unsigned)f2bf(v0.w) << 16) | f2bf(v0.z);
    unsigned p2 = ((unsigned)f2bf(v1.y) << 16) | f2bf(v1.x);
    unsigned p3 = ((unsigned)f2bf(v1.w) << 16) | f2bf(v1.z);
    *(i32x4*)&xt[rr][cc][0] = (i32x4){(int)p0, (int)p1, (int)p2, (int)p3};
  }

  const unsigned short* wrow = wct + (size_t)ch * KP;
  const unsigned short* xtf  = &xt[0][0][0];

  __syncthreads();

#define ROWSTR (XC * CIN)            // 304 elements per staged row

#pragma unroll 1
  for (int sub = 0; sub < 2; ++sub) {        // 4-row quad: m0..m0+3
    const int m0 = rg * 8 + sub * 4;
    f32x16 acc0 = {}, acc1 = {}, acc2 = {}, acc3 = {};
    const int mbase = m0 * ROWSTR + l31 * CIN;

#pragma unroll 1                     // phase-local weight sets (5 frags = 20 VGPR)
    for (int sp = 0; sp < 5; ++sp) {
      bf16x8 wf[5];
#pragma unroll
      for (int s2 = 0; s2 < 5; ++s2)         // A-frag: wct[ch][16s + 8hi ..+7]
        wf[s2] = ld16s(&wrow[80 * sp + 16 * s2 + 8 * hi]);
#pragma unroll
      for (int s2 = 0; s2 < 5; ++s2) {
        int p = 10 * sp + 2 * s2 + hi;       // pair index 0..49
        int pc = p > 48 ? 48 : p;            // pair 49: zero weight; clamp addr
        int th = (pc * 9363) >> 16;          // /7 magic (exact for pc<=48)
        int tw = pc - 7 * th;
        const unsigned short* bp = xtf + mbase + th * ROWSTR + tw * CIN;
        acc0 = mfma32(wf[s2], ld16s(bp), acc0);
        acc1 = mfma32(wf[s2], ld16s(bp + ROWSTR), acc1);
        acc2 = mfma32(wf[s2], ld16s(bp + 2 * ROWSTR), acc2);
        acc3 = mfma32(wf[s2], ld16s(bp + 3 * ROWSTR), acc3);
      }
    }

    // ---- epilogue: PLAIN stores (L2 merges 32B halves into full lines) ----
#define EPI(R, ACC)                                                               \
    {                                                                             \
      const size_t ob = (((size_t)b * H_ + h0 + m0 + (R)) * W_ + w0 + l31) * COUT \
                        + cht * 32 + 4 * hi;                                      \
      _Pragma("unroll")                                                           \
      for (int q = 0; q < 4; ++q) {                                               \
        const float4 bia = *(const float4*)&bias2e[cht * 32 + 8 * q + 4 * hi];    \
        f32x4 v = {(ACC)[4 * q] + bia.x, (ACC)[4 * q + 1] + bia.y,                \
                   (ACC)[4 * q + 2] + bia.z, (ACC)[4 * q + 3] + bia.w};           \
        *(f32x4*)(out + ob + 8 * q) = v;                                          \
      }                                                                           \
    }
    EPI(0, acc0) EPI(1, acc1) EPI(2, acc2) EPI(3, acc3)
#undef EPI
  }
}

extern "C" void kernel_launch(void* const* d_in, const int* in_sizes, int n_in,
                              void* d_out, int out_size, void* d_ws, size_t ws_size,
                              hipStream_t stream) {
  const float* x  = (const float*)d_in[0];
  const float* W1 = (const float*)d_in[1];
  const float* b1 = (const float*)d_in[2];
  const float* W2 = (const float*)d_in[3];
  const float* b2 = (const float*)d_in[4];
  // d_in[5] = training (unused)

  unsigned short* wct = (unsigned short*)d_ws;       // 96*400 u16
  float* bias2e = (float*)(wct + 96 * KP);           // 96 f32
  float* out = (float*)d_out;

  prep_kernel<<<dim3(150), dim3(256), 0, stream>>>(W1, b1, W2, b2, wct, bias2e);
  conv7<<<dim3(W_ / TW, H_ / TH, B_), dim3(NTHREADS), 0, stream>>>(
      x, wct, bias2e, out);
}